// Round 7
// baseline (184618.787 us; speedup 1.0000x reference)
//
#include <hip/hip_runtime.h>

#define S_LEN 32768
#define EMB   256
#define HID   512
#define G3H   1536   // 3*HID
#define NBLK  1024   // launched; 32 claim ranks (XCD-0 blocks, tail fallback)
#define NRANK 32
#define NTAIL 48
#define NTHR  512
#define NOUT  8

// ws layout (float units):
// [0, 9216)        gx_table (6 x 1536)  : emb@W_ih.T + b_ih
// [9216, 11264)    hbuf: 2 x 512 tagged u64 words. word = (tag<<32)|f32bits
// [11264]          claim counter (int)
#define WS_GX    0
#define WS_HBUF  9216
#define WS_CLAIM 11264

__global__ __launch_bounds__(256) void gru_precompute_kernel(
    const float* __restrict__ emb, const float* __restrict__ W_ih,
    const float* __restrict__ b_ih, float* __restrict__ ws)
{
    int idx = blockIdx.x * 256 + threadIdx.x;
    if (idx < 6 * G3H) {
        int v = idx / G3H, r = idx - v * G3H;
        const float* er = emb + v * EMB;
        const float* wr = W_ih + r * EMB;
        float s = 0.f;
        #pragma unroll 8
        for (int e = 0; e < EMB; ++e) s += er[e] * wr[e];
        ws[WS_GX + idx] = s + b_ih[r];
    }
    if (blockIdx.x == 0) {
        // re-zero h tags (h_0 = 0, tag 0) and the claim counter every launch
        for (int j = threadIdx.x; j < 2048; j += 256)
            __hip_atomic_store((int*)&ws[WS_HBUF + j], 0,
                               __ATOMIC_RELAXED, __HIP_MEMORY_SCOPE_AGENT);
        if (threadIdx.x == 0)
            __hip_atomic_store((int*)&ws[WS_CLAIM], 0,
                               __ATOMIC_RELAXED, __HIP_MEMORY_SCOPE_AGENT);
    }
}

// Persistent GRU, XCD-local by construction: blocks read HW_REG_XCC_ID and
// only XCD-0 blocks claim one of 32 ranks (tail blocks eligible as fallback).
// Rank r owns h rows [16r, 16r+16). Wave w owns rows 16r+2w+{0,1}: half-wave
// hh = l>>5 takes one row, lane ll = l&31 owns cols {ll,ll+32,ll+64,ll+96}
// (float4 units) = 4 float4 x 3 gates = 48 weight VGPRs, register-resident.
// Exchange: tagged (tag<<32|f32bits) u64. Producer double-stores (sc0 = own-L2
// fast path, sc0 sc1 = MALL safety). Consumer polls sc0 with every-8th sc0 sc1
// escalation: XCD-local -> ~200cy discovery; mixed (fallback) -> correct via
// escalation (round-4 validated), just slower. Back-pressure: parity double
// buffer + per-WG barrier; a WG reaches t+2 only after every WG consumed t.
__global__ __launch_bounds__(512, 1) void gru_persistent_kernel(
    const int* __restrict__ seq, const float* __restrict__ W_hh,
    const float* __restrict__ b_hh, const float* __restrict__ W_out,
    const float* __restrict__ b_out, float* __restrict__ ws,
    float* __restrict__ out)
{
    const int tid = threadIdx.x;

    // physical XCD id of this block [measured: learn_hip m09]
    unsigned xcc;
    asm volatile("s_getreg_b32 %0, hwreg(HW_REG_XCC_ID)" : "=s"(xcc));

    __shared__ int rank_sh;
    if (tid == 0) {
        int rk = -1;
        if (xcc == 0 || blockIdx.x >= NBLK - NTAIL)
            rk = atomicAdd((int*)&ws[WS_CLAIM], 1);   // device-scope RMW
        rank_sh = rk;
    }
    __syncthreads();
    const int r = rank_sh;
    if (r < 0 || r >= NRANK) return;

    const int w  = tid >> 6;          // wave 0..7
    const int l  = tid & 63;
    const int hh = l >> 5;            // half-wave -> row select
    const int ll = l & 31;            // lane in half-wave -> column slice
    const int lr = 2 * w + hh;        // local row 0..15
    const int row = r * 16 + lr;      // global h row

    __shared__ __align__(16) float h_lds[2][HID];
    __shared__ float gx_lds[6 * 48];  // [v][gate][lr], b_hh folded for r,z
    __shared__ unsigned char seq_lds[S_LEN];

    unsigned long long* hbuf = (unsigned long long*)(ws + WS_HBUF);

    // ---- one-time weight load: 12 named float4 = 48 VGPRs ----
    const float4* W4 = (const float4*)W_hh;        // 128 float4 per 512-col row
    const size_t br = (size_t)(0 * HID + row) * 128;
    const size_t bz = (size_t)(1 * HID + row) * 128;
    const size_t bn = (size_t)(2 * HID + row) * 128;
    float4 WR0 = W4[br + ll], WR1 = W4[br + 32 + ll],
           WR2 = W4[br + 64 + ll], WR3 = W4[br + 96 + ll];
    float4 WZ0 = W4[bz + ll], WZ1 = W4[bz + 32 + ll],
           WZ2 = W4[bz + 64 + ll], WZ3 = W4[bz + 96 + ll];
    float4 WN0 = W4[bn + ll], WN1 = W4[bn + 32 + ll],
           WN2 = W4[bn + 64 + ll], WN3 = W4[bn + 96 + ll];
    const float bhn = b_hh[2 * HID + row];

    // ---- one-time LDS staging ----
    if (tid < 6 * 48) {
        int v = tid / 48, rem = tid - v * 48, gate = rem >> 4, j = rem & 15;
        float val = ws[WS_GX + v * G3H + gate * HID + r * 16 + j];
        if (gate < 2) val += b_hh[gate * HID + r * 16 + j];  // fold b_hh for r,z
        gx_lds[tid] = val;
    }
    for (int q = tid; q < S_LEN; q += NTHR) seq_lds[q] = (unsigned char)seq[q];
    __syncthreads();

    for (int t = 0; t < S_LEN; ++t) {
        const int p = t & 1;
        int v = seq_lds[t];
        float gxr = gx_lds[v * 48 + lr];
        float gxz = gx_lds[v * 48 + 16 + lr];
        float gxn = gx_lds[v * 48 + 32 + lr];

        // poll own tagged word: sc0 fast path, every-8th sc0 sc1 escalation
        {
            const unsigned long long* src = &hbuf[p * HID + tid];
            unsigned long long hw_;
            int spin = 0;
            for (;;) {
                if ((spin++ & 7) == 7)
                    asm volatile("global_load_dwordx2 %0, %1, off sc0 sc1\n\t"
                                 "s_waitcnt vmcnt(0)"
                                 : "=v"(hw_) : "v"(src));
                else
                    asm volatile("global_load_dwordx2 %0, %1, off sc0\n\t"
                                 "s_waitcnt vmcnt(0)"
                                 : "=v"(hw_) : "v"(src));
                if ((unsigned)(hw_ >> 32) == (unsigned)t) break;
            }
            h_lds[p][tid] = __uint_as_float((unsigned)hw_);
        }
        __syncthreads();   // sole barrier per step (parity double buffer)

        // dot over this lane's 16 columns (4 float4), 3 gates
        const float4* h4 = (const float4*)&h_lds[p][0];
        float4 h0 = h4[ll], h1 = h4[32 + ll], h2 = h4[64 + ll], h3 = h4[96 + ll];
        float ar = WR0.x*h0.x + WR0.y*h0.y + WR0.z*h0.z + WR0.w*h0.w
                 + WR1.x*h1.x + WR1.y*h1.y + WR1.z*h1.z + WR1.w*h1.w
                 + WR2.x*h2.x + WR2.y*h2.y + WR2.z*h2.z + WR2.w*h2.w
                 + WR3.x*h3.x + WR3.y*h3.y + WR3.z*h3.z + WR3.w*h3.w;
        float az = WZ0.x*h0.x + WZ0.y*h0.y + WZ0.z*h0.z + WZ0.w*h0.w
                 + WZ1.x*h1.x + WZ1.y*h1.y + WZ1.z*h1.z + WZ1.w*h1.w
                 + WZ2.x*h2.x + WZ2.y*h2.y + WZ2.z*h2.z + WZ2.w*h2.w
                 + WZ3.x*h3.x + WZ3.y*h3.y + WZ3.z*h3.z + WZ3.w*h3.w;
        float an = WN0.x*h0.x + WN0.y*h0.y + WN0.z*h0.z + WN0.w*h0.w
                 + WN1.x*h1.x + WN1.y*h1.y + WN1.z*h1.z + WN1.w*h1.w
                 + WN2.x*h2.x + WN2.y*h2.y + WN2.z*h2.z + WN2.w*h2.w
                 + WN3.x*h3.x + WN3.y*h3.y + WN3.z*h3.z + WN3.w*h3.w;

        // butterfly reduce within the 32-lane half-wave
        #pragma unroll
        for (int m = 1; m < 32; m <<= 1) {
            ar += __shfl_xor(ar, m, 64);
            az += __shfl_xor(az, m, 64);
            an += __shfl_xor(an, m, 64);
        }

        float rg = __fdividef(1.f, 1.f + __expf(-(gxr + ar)));
        float zg = __fdividef(1.f, 1.f + __expf(-(gxz + az)));
        float nx = gxn + rg * (an + bhn);
        float ng = 1.f - __fdividef(2.f, 1.f + __expf(2.f * nx));  // tanh
        float hold = h_lds[p][row];        // broadcast read
        float hn = (1.f - zg) * ng + zg * hold;

        if (ll == 0) {
            unsigned long long wo =
                ((unsigned long long)(unsigned)(t + 1) << 32) |
                (unsigned long long)__float_as_uint(hn);
            unsigned long long* dst = &hbuf[(1 - p) * HID + row];
            asm volatile("global_store_dwordx2 %0, %1, off sc0\n\t"
                         "global_store_dwordx2 %0, %1, off sc0 sc1"
                         :: "v"(dst), "v"(wo));
        }
        // no trailing barrier: next step stages into h_lds[1-p]
    }

    // ---- epilogue: rank-0 WG computes out = W_out @ h_T + b_out ----
    if (r == 0) {
        // h_{S_LEN} lives in parity 0 with tag S_LEN
        const unsigned long long* src = &hbuf[0 * HID + tid];
        unsigned long long hw_;
        int spin = 0;
        for (;;) {
            if ((spin++ & 7) == 7)
                asm volatile("global_load_dwordx2 %0, %1, off sc0 sc1\n\t"
                             "s_waitcnt vmcnt(0)"
                             : "=v"(hw_) : "v"(src));
            else
                asm volatile("global_load_dwordx2 %0, %1, off sc0\n\t"
                             "s_waitcnt vmcnt(0)"
                             : "=v"(hw_) : "v"(src));
            if ((unsigned)(hw_ >> 32) == (unsigned)S_LEN) break;
        }
        h_lds[0][tid] = __uint_as_float((unsigned)hw_);
        __syncthreads();
        // wave w computes out[w] (NOUT == 8 == waves per WG)
        float s = 0.f;
        #pragma unroll
        for (int m = 0; m < 8; ++m) {
            int j = l + 64 * m;
            s += W_out[w * HID + j] * h_lds[0][j];
        }
        #pragma unroll
        for (int m = 1; m < 64; m <<= 1) s += __shfl_xor(s, m, 64);
        if (l == 0) out[w] = s + b_out[w];
    }
}

extern "C" void kernel_launch(void* const* d_in, const int* in_sizes, int n_in,
                              void* d_out, int out_size, void* d_ws, size_t ws_size,
                              hipStream_t stream) {
    const int*   seq   = (const int*)d_in[0];
    const float* emb   = (const float*)d_in[1];
    const float* W_ih  = (const float*)d_in[2];
    const float* W_hh  = (const float*)d_in[3];
    const float* b_ih  = (const float*)d_in[4];
    const float* b_hh  = (const float*)d_in[5];
    const float* W_out = (const float*)d_in[6];
    const float* b_out = (const float*)d_in[7];
    float* ws = (float*)d_ws;
    float* out = (float*)d_out;

    gru_precompute_kernel<<<36, 256, 0, stream>>>(emb, W_ih, b_ih, ws);
    gru_persistent_kernel<<<NBLK, NTHR, 0, stream>>>(seq, W_hh, b_hh, W_out, b_out,
                                                     ws, out);
}

// Round 8
// 78260.315 us; speedup vs baseline: 2.3590x; 2.3590x over previous
//
#include <hip/hip_runtime.h>

#define S_LEN 32768
#define EMB   256
#define HID   512
#define G3H   1536   // 3*HID
#define NWG   16
#define NTHR  1024
#define NOUT  8

// ws layout (float units):
// [0, 9216)        gx_table (6 x 1536)  : emb@W_ih.T + b_ih
// [9216, 11264)    hbuf: 2 x 512 tagged u64 words. word = (tag<<32)|f32bits
#define WS_GX    0
#define WS_HBUF  9216

__global__ __launch_bounds__(256) void gru_precompute_kernel(
    const float* __restrict__ emb, const float* __restrict__ W_ih,
    const float* __restrict__ b_ih, float* __restrict__ ws)
{
    int idx = blockIdx.x * 256 + threadIdx.x;
    if (idx < 6 * G3H) {
        int v = idx / G3H, r = idx - v * G3H;
        const float* er = emb + v * EMB;
        const float* wr = W_ih + r * EMB;
        float s = 0.f;
        #pragma unroll 8
        for (int e = 0; e < EMB; ++e) s += er[e] * wr[e];
        ws[WS_GX + idx] = s + b_ih[r];
    }
    if (blockIdx.x == 0) {
        // re-zero the tagged h buffer (tag 0 == h_0 == 0) every launch so
        // graph replays never see stale tags (proven in rounds 3/6).
        for (int j = threadIdx.x; j < 2048; j += 256)
            __hip_atomic_store((int*)&ws[WS_HBUF + j], 0,
                               __ATOMIC_RELAXED, __HIP_MEMORY_SCOPE_AGENT);
    }
}

// Persistent GRU: 16 WGs x 1024 threads. WG r owns h rows [32r, 32r+32).
// Wave w owns rows 32r+2w+{0,1}: half-wave hh=l>>5 takes one row, lane
// ll=l&31 owns float4-columns {ll, ll+32, ll+64, ll+96} = 12 float4 = 48
// weight VGPRs/lane (residency proven in rounds 6/7 at this footprint).
// Exchange (round-3 protocol verbatim): tagged (tag<<32|f32bits) u64 via
// relaxed agent-scope __hip_atomic load/store; consumers poll for exact tag.
// Only threads 0..511 poll (8K pollers device-wide, half of round 3's best
// behaviour per word); parity-double-buffered h_lds, ONE barrier per step.
// Back-pressure: WG stores tags t+1 only after observing all tags t, so a
// fast WG can never overwrite a word a slow WG has not yet consumed.
__global__ __launch_bounds__(1024, 1) void gru_persistent_kernel(
    const int* __restrict__ seq, const float* __restrict__ W_hh,
    const float* __restrict__ b_hh, const float* __restrict__ W_out,
    const float* __restrict__ b_out, float* __restrict__ ws,
    float* __restrict__ out)
{
    const int r   = blockIdx.x;          // 0..15
    const int tid = threadIdx.x;
    const int w   = tid >> 6;            // wave 0..15
    const int l   = tid & 63;
    const int hh  = l >> 5;              // half-wave -> row select
    const int ll  = l & 31;              // lane in half-wave -> column slice
    const int lr  = 2 * w + hh;          // local row 0..31
    const int row = r * 32 + lr;         // global h row

    __shared__ __align__(16) float h_lds[2][HID];
    __shared__ float gx_lds[6 * 96];     // [v][gate][lr], b_hh folded for r,z
    __shared__ unsigned char seq_lds[S_LEN];

    unsigned long long* hbuf = (unsigned long long*)(ws + WS_HBUF);

    // ---- one-time weight load: 12 named float4 = 48 VGPRs ----
    const float4* W4 = (const float4*)W_hh;        // 128 float4 per 512-col row
    const size_t br = (size_t)(0 * HID + row) * 128;
    const size_t bz = (size_t)(1 * HID + row) * 128;
    const size_t bn = (size_t)(2 * HID + row) * 128;
    float4 WR0 = W4[br + ll], WR1 = W4[br + 32 + ll],
           WR2 = W4[br + 64 + ll], WR3 = W4[br + 96 + ll];
    float4 WZ0 = W4[bz + ll], WZ1 = W4[bz + 32 + ll],
           WZ2 = W4[bz + 64 + ll], WZ3 = W4[bz + 96 + ll];
    float4 WN0 = W4[bn + ll], WN1 = W4[bn + 32 + ll],
           WN2 = W4[bn + 64 + ll], WN3 = W4[bn + 96 + ll];
    const float bhn = b_hh[2 * HID + row];

    // ---- one-time LDS staging ----
    if (tid < 6 * 96) {
        int v = tid / 96, rem = tid - v * 96, gate = rem >> 5, j = rem & 31;
        float val = ws[WS_GX + v * G3H + gate * HID + r * 32 + j];
        if (gate < 2) val += b_hh[gate * HID + r * 32 + j];  // fold b_hh for r,z
        gx_lds[tid] = val;
    }
    for (int q = tid; q < S_LEN; q += NTHR) seq_lds[q] = (unsigned char)seq[q];
    __syncthreads();

    for (int t = 0; t < S_LEN; ++t) {
        const int p = t & 1;
        // h-independent prefetch
        int v = seq_lds[t];
        float gxr = gx_lds[v * 96 + lr];
        float gxz = gx_lds[v * 96 + 32 + lr];
        float gxn = gx_lds[v * 96 + 64 + lr];

        // poll phase: threads 0..511 each own one h word
        if (tid < HID) {
            unsigned long long hw;
            do {
                hw = __hip_atomic_load(&hbuf[p * HID + tid], __ATOMIC_RELAXED,
                                       __HIP_MEMORY_SCOPE_AGENT);
            } while ((unsigned)(hw >> 32) != (unsigned)t);
            h_lds[p][tid] = __uint_as_float((unsigned)hw);
        }
        __syncthreads();   // sole barrier per step (parity double buffer)

        // dot over this lane's 16 columns (4 float4), 3 gates
        const float4* h4 = (const float4*)&h_lds[p][0];
        float4 h0 = h4[ll], h1 = h4[32 + ll], h2 = h4[64 + ll], h3 = h4[96 + ll];
        float ar = WR0.x*h0.x + WR0.y*h0.y + WR0.z*h0.z + WR0.w*h0.w
                 + WR1.x*h1.x + WR1.y*h1.y + WR1.z*h1.z + WR1.w*h1.w
                 + WR2.x*h2.x + WR2.y*h2.y + WR2.z*h2.z + WR2.w*h2.w
                 + WR3.x*h3.x + WR3.y*h3.y + WR3.z*h3.z + WR3.w*h3.w;
        float az = WZ0.x*h0.x + WZ0.y*h0.y + WZ0.z*h0.z + WZ0.w*h0.w
                 + WZ1.x*h1.x + WZ1.y*h1.y + WZ1.z*h1.z + WZ1.w*h1.w
                 + WZ2.x*h2.x + WZ2.y*h2.y + WZ2.z*h2.z + WZ2.w*h2.w
                 + WZ3.x*h3.x + WZ3.y*h3.y + WZ3.z*h3.z + WZ3.w*h3.w;
        float an = WN0.x*h0.x + WN0.y*h0.y + WN0.z*h0.z + WN0.w*h0.w
                 + WN1.x*h1.x + WN1.y*h1.y + WN1.z*h1.z + WN1.w*h1.w
                 + WN2.x*h2.x + WN2.y*h2.y + WN2.z*h2.z + WN2.w*h2.w
                 + WN3.x*h3.x + WN3.y*h3.y + WN3.z*h3.z + WN3.w*h3.w;

        // butterfly reduce within the 32-lane half-wave (masks stay in half)
        #pragma unroll
        for (int m = 1; m < 32; m <<= 1) {
            ar += __shfl_xor(ar, m, 64);
            az += __shfl_xor(az, m, 64);
            an += __shfl_xor(an, m, 64);
        }

        float rg = __fdividef(1.f, 1.f + __expf(-(gxr + ar)));
        float zg = __fdividef(1.f, 1.f + __expf(-(gxz + az)));
        float nx = gxn + rg * (an + bhn);
        float ng = 1.f - __fdividef(2.f, 1.f + __expf(2.f * nx));  // tanh
        float hold = h_lds[p][row];        // broadcast read
        float hn = (1.f - zg) * ng + zg * hold;

        if (ll == 0) {
            unsigned long long wo =
                ((unsigned long long)(unsigned)(t + 1) << 32) |
                (unsigned long long)__float_as_uint(hn);
            __hip_atomic_store(&hbuf[(1 - p) * HID + row], wo,
                               __ATOMIC_RELAXED, __HIP_MEMORY_SCOPE_AGENT);
        }
        // no trailing barrier: next step stages into h_lds[1-p]
    }

    // ---- epilogue: WG 0 computes out = W_out @ h_T + b_out ----
    if (r == 0) {
        // h_{S_LEN} lives in parity 0 with tag S_LEN
        if (tid < HID) {
            unsigned long long hw;
            do {
                hw = __hip_atomic_load(&hbuf[0 * HID + tid], __ATOMIC_RELAXED,
                                       __HIP_MEMORY_SCOPE_AGENT);
            } while ((unsigned)(hw >> 32) != (unsigned)S_LEN);
            h_lds[0][tid] = __uint_as_float((unsigned)hw);
        }
        __syncthreads();
        // waves 0..7 compute out[0..7]
        if (w < NOUT) {
            float s = 0.f;
            #pragma unroll
            for (int m = 0; m < 8; ++m) {
                int j = l + 64 * m;
                s += W_out[w * HID + j] * h_lds[0][j];
            }
            #pragma unroll
            for (int m = 1; m < 64; m <<= 1) s += __shfl_xor(s, m, 64);
            if (l == 0) out[w] = s + b_out[w];
        }
    }
}

extern "C" void kernel_launch(void* const* d_in, const int* in_sizes, int n_in,
                              void* d_out, int out_size, void* d_ws, size_t ws_size,
                              hipStream_t stream) {
    const int*   seq   = (const int*)d_in[0];
    const float* emb   = (const float*)d_in[1];
    const float* W_ih  = (const float*)d_in[2];
    const float* W_hh  = (const float*)d_in[3];
    const float* b_ih  = (const float*)d_in[4];
    const float* b_hh  = (const float*)d_in[5];
    const float* W_out = (const float*)d_in[6];
    const float* b_out = (const float*)d_in[7];
    float* ws = (float*)d_ws;
    float* out = (float*)d_out;

    gru_precompute_kernel<<<36, 256, 0, stream>>>(emb, W_ih, b_ih, ws);
    gru_persistent_kernel<<<NWG, NTHR, 0, stream>>>(seq, W_hh, b_hh, W_out, b_out,
                                                    ws, out);
}

// Round 10
// 69889.636 us; speedup vs baseline: 2.6416x; 1.1198x over previous
//
#include <hip/hip_runtime.h>

#define S_LEN 32768
#define EMB   256
#define HID   512
#define G3H   1536   // 3*HID
#define NWG   16
#define NTHR  512
#define NOUT  8

// ws layout (float units):
// [0, 9216)        gx_table (6 x 1536)  : emb@W_ih.T + b_ih
// [9216, 11264)    hbuf: 2 x 512 tagged u64 words. word = (tag<<32)|f32bits
#define WS_GX    0
#define WS_HBUF  9216

__global__ __launch_bounds__(256) void gru_precompute_kernel(
    const float* __restrict__ emb, const float* __restrict__ W_ih,
    const float* __restrict__ b_ih, float* __restrict__ ws)
{
    int idx = blockIdx.x * 256 + threadIdx.x;
    if (idx < 6 * G3H) {
        int v = idx / G3H, r = idx - v * G3H;
        const float* er = emb + v * EMB;
        const float* wr = W_ih + r * EMB;
        float s = 0.f;
        #pragma unroll 8
        for (int e = 0; e < EMB; ++e) s += er[e] * wr[e];
        ws[WS_GX + idx] = s + b_ih[r];
    }
    if (blockIdx.x == 0) {
        // re-zero the tagged h buffer (tag 0 == h_0 == 0) every launch so
        // graph replays never see stale tags (proven rounds 3/6/8).
        for (int j = threadIdx.x; j < 2048; j += 256)
            __hip_atomic_store((int*)&ws[WS_HBUF + j], 0,
                               __ATOMIC_RELAXED, __HIP_MEMORY_SCOPE_AGENT);
    }
}

// Persistent GRU: 16 WGs x 512 threads. WG r owns h rows [32r, 32r+32).
// Wave w owns rows 32r + 4w + qq (qq = quarter-wave, l>>4); lane ll = l&15
// owns float4-columns {ll + 16*cc} with per-quarter rotated chunk order
// (co = 2*qq) so the four quarters read disjoint 256B LDS regions.
// Weights: 24 NAMED float4 = 96 VGPRs, pinned once via "+v" asm (no asm in
// the loop). Exchange: tagged (tag<<32|f32bits) u64 via relaxed agent-scope
// __hip_atomic (the only protocol that progresses at native RTT; sc0 asm
// refuted in R4/R5/R7). One GATHER WAVE per WG polls all 512 words
// (64 lanes x 8 words, independent in-flight loads, per-word tag retry) and
// stages to LDS; the other 7 waves wait at the barrier, off the fabric.
// Back-pressure: a WG publishes tag t+1 only after its own full t-gather,
// and gathering t from every WG implies every WG finished gathering t-1 —
// so a tag t-1 slot is never overwritten before all WGs consumed it.
// R9 BUG FIXED: gx staging is a strided loop (576 entries > 512 threads;
// the single-conditional version left vocab-5 z/n preactivations garbage).
__global__ __launch_bounds__(512, 2) void gru_persistent_kernel(
    const int* __restrict__ seq, const float* __restrict__ W_hh,
    const float* __restrict__ b_hh, const float* __restrict__ W_out,
    const float* __restrict__ b_out, float* __restrict__ ws,
    float* __restrict__ out)
{
    const int r   = blockIdx.x;          // 0..15
    const int tid = threadIdx.x;
    const int w   = tid >> 6;            // wave 0..7
    const int l   = tid & 63;
    const int qq  = l >> 4;              // quarter-wave -> row select
    const int ll  = l & 15;              // lane in quarter -> column slice
    const int lr  = 4 * w + qq;          // local row 0..31
    const int row = r * 32 + lr;         // global h row
    const int co  = 2 * qq;              // chunk rotation offset

    __shared__ __align__(16) float h_lds[2][HID];
    __shared__ float gx_lds[6 * 96];     // [v][gate][lr], b_hh folded for r,z
    __shared__ unsigned char seq_lds[S_LEN];

    unsigned long long* hbuf = (unsigned long long*)(ws + WS_HBUF);

    // ---- one-time weight load: 24 named float4 (chunk cc = (c+co)&7) ----
    const float4* W4 = (const float4*)W_hh;        // 128 float4 per 512-col row
    const size_t br = (size_t)(0 * HID + row) * 128;
    const size_t bz = (size_t)(1 * HID + row) * 128;
    const size_t bn = (size_t)(2 * HID + row) * 128;
    float4 WR0 = W4[br + ll + 16 * ((0 + co) & 7)], WZ0 = W4[bz + ll + 16 * ((0 + co) & 7)], WN0 = W4[bn + ll + 16 * ((0 + co) & 7)];
    float4 WR1 = W4[br + ll + 16 * ((1 + co) & 7)], WZ1 = W4[bz + ll + 16 * ((1 + co) & 7)], WN1 = W4[bn + ll + 16 * ((1 + co) & 7)];
    float4 WR2 = W4[br + ll + 16 * ((2 + co) & 7)], WZ2 = W4[bz + ll + 16 * ((2 + co) & 7)], WN2 = W4[bn + ll + 16 * ((2 + co) & 7)];
    float4 WR3 = W4[br + ll + 16 * ((3 + co) & 7)], WZ3 = W4[bz + ll + 16 * ((3 + co) & 7)], WN3 = W4[bn + ll + 16 * ((3 + co) & 7)];
    float4 WR4 = W4[br + ll + 16 * ((4 + co) & 7)], WZ4 = W4[bz + ll + 16 * ((4 + co) & 7)], WN4 = W4[bn + ll + 16 * ((4 + co) & 7)];
    float4 WR5 = W4[br + ll + 16 * ((5 + co) & 7)], WZ5 = W4[bz + ll + 16 * ((5 + co) & 7)], WN5 = W4[bn + ll + 16 * ((5 + co) & 7)];
    float4 WR6 = W4[br + ll + 16 * ((6 + co) & 7)], WZ6 = W4[bz + ll + 16 * ((6 + co) & 7)], WN6 = W4[bn + ll + 16 * ((6 + co) & 7)];
    float4 WR7 = W4[br + ll + 16 * ((7 + co) & 7)], WZ7 = W4[bz + ll + 16 * ((7 + co) & 7)], WN7 = W4[bn + ll + 16 * ((7 + co) & 7)];
    const float bhn = b_hh[2 * HID + row];

    // pin once: forbid remat/sinking of the loads into the t-loop (R8: the
    // allocator otherwise re-loads weights from L2 every step, VGPR=48)
    #define PIN4(V) asm("" : "+v"(V.x), "+v"(V.y), "+v"(V.z), "+v"(V.w))
    PIN4(WR0); PIN4(WR1); PIN4(WR2); PIN4(WR3); PIN4(WR4); PIN4(WR5); PIN4(WR6); PIN4(WR7);
    PIN4(WZ0); PIN4(WZ1); PIN4(WZ2); PIN4(WZ3); PIN4(WZ4); PIN4(WZ5); PIN4(WZ6); PIN4(WZ7);
    PIN4(WN0); PIN4(WN1); PIN4(WN2); PIN4(WN3); PIN4(WN4); PIN4(WN5); PIN4(WN6); PIN4(WN7);
    #undef PIN4

    // ---- one-time LDS staging (STRIDED: 576 entries, 512 threads) ----
    for (int idx = tid; idx < 6 * 96; idx += NTHR) {
        int v = idx / 96, rem = idx - v * 96, gate = rem >> 5, j = rem & 31;
        float val = ws[WS_GX + v * G3H + gate * HID + r * 32 + j];
        if (gate < 2) val += b_hh[gate * HID + r * 32 + j];  // fold b_hh for r,z
        gx_lds[idx] = val;
    }
    for (int q = tid; q < S_LEN; q += NTHR) seq_lds[q] = (unsigned char)seq[q];
    __syncthreads();

    for (int t = 0; t < S_LEN; ++t) {
        const int p = t & 1;
        // h-independent prefetch
        int v = seq_lds[t];
        float gxr = gx_lds[v * 96 + lr];
        float gxz = gx_lds[v * 96 + 32 + lr];
        float gxn = gx_lds[v * 96 + 64 + lr];

        // ---- gather phase: wave 0 polls all 512 words (8 per lane) ----
        if (w == 0) {
            const unsigned long long* base = &hbuf[p * HID];
            unsigned long long v0, v1, v2, v3, v4, v5, v6, v7;
            unsigned pend = 0xFFu;
            do {
                if (pend & 0x01u) v0 = __hip_atomic_load(&base[l + 0 * 64], __ATOMIC_RELAXED, __HIP_MEMORY_SCOPE_AGENT);
                if (pend & 0x02u) v1 = __hip_atomic_load(&base[l + 1 * 64], __ATOMIC_RELAXED, __HIP_MEMORY_SCOPE_AGENT);
                if (pend & 0x04u) v2 = __hip_atomic_load(&base[l + 2 * 64], __ATOMIC_RELAXED, __HIP_MEMORY_SCOPE_AGENT);
                if (pend & 0x08u) v3 = __hip_atomic_load(&base[l + 3 * 64], __ATOMIC_RELAXED, __HIP_MEMORY_SCOPE_AGENT);
                if (pend & 0x10u) v4 = __hip_atomic_load(&base[l + 4 * 64], __ATOMIC_RELAXED, __HIP_MEMORY_SCOPE_AGENT);
                if (pend & 0x20u) v5 = __hip_atomic_load(&base[l + 5 * 64], __ATOMIC_RELAXED, __HIP_MEMORY_SCOPE_AGENT);
                if (pend & 0x40u) v6 = __hip_atomic_load(&base[l + 6 * 64], __ATOMIC_RELAXED, __HIP_MEMORY_SCOPE_AGENT);
                if (pend & 0x80u) v7 = __hip_atomic_load(&base[l + 7 * 64], __ATOMIC_RELAXED, __HIP_MEMORY_SCOPE_AGENT);
                if ((pend & 0x01u) && (unsigned)(v0 >> 32) == (unsigned)t) { h_lds[p][l + 0 * 64] = __uint_as_float((unsigned)v0); pend &= ~0x01u; }
                if ((pend & 0x02u) && (unsigned)(v1 >> 32) == (unsigned)t) { h_lds[p][l + 1 * 64] = __uint_as_float((unsigned)v1); pend &= ~0x02u; }
                if ((pend & 0x04u) && (unsigned)(v2 >> 32) == (unsigned)t) { h_lds[p][l + 2 * 64] = __uint_as_float((unsigned)v2); pend &= ~0x04u; }
                if ((pend & 0x08u) && (unsigned)(v3 >> 32) == (unsigned)t) { h_lds[p][l + 3 * 64] = __uint_as_float((unsigned)v3); pend &= ~0x08u; }
                if ((pend & 0x10u) && (unsigned)(v4 >> 32) == (unsigned)t) { h_lds[p][l + 4 * 64] = __uint_as_float((unsigned)v4); pend &= ~0x10u; }
                if ((pend & 0x20u) && (unsigned)(v5 >> 32) == (unsigned)t) { h_lds[p][l + 5 * 64] = __uint_as_float((unsigned)v5); pend &= ~0x20u; }
                if ((pend & 0x40u) && (unsigned)(v6 >> 32) == (unsigned)t) { h_lds[p][l + 6 * 64] = __uint_as_float((unsigned)v6); pend &= ~0x40u; }
                if ((pend & 0x80u) && (unsigned)(v7 >> 32) == (unsigned)t) { h_lds[p][l + 7 * 64] = __uint_as_float((unsigned)v7); pend &= ~0x80u; }
            } while (pend);
        }
        __syncthreads();   // sole barrier per step (parity double buffer)

        // ---- dot over this lane's 32 columns (8 rotated float4), 3 gates ----
        const float4* h4 = (const float4*)&h_lds[p][0];
        float4 h0 = h4[ll + 16 * ((0 + co) & 7)];
        float4 h1 = h4[ll + 16 * ((1 + co) & 7)];
        float4 h2 = h4[ll + 16 * ((2 + co) & 7)];
        float4 h3 = h4[ll + 16 * ((3 + co) & 7)];
        float4 h4v = h4[ll + 16 * ((4 + co) & 7)];
        float4 h5 = h4[ll + 16 * ((5 + co) & 7)];
        float4 h6 = h4[ll + 16 * ((6 + co) & 7)];
        float4 h7 = h4[ll + 16 * ((7 + co) & 7)];
        float ar, az, an;
        ar  = WR0.x*h0.x + WR0.y*h0.y + WR0.z*h0.z + WR0.w*h0.w;
        ar += WR1.x*h1.x + WR1.y*h1.y + WR1.z*h1.z + WR1.w*h1.w;
        ar += WR2.x*h2.x + WR2.y*h2.y + WR2.z*h2.z + WR2.w*h2.w;
        ar += WR3.x*h3.x + WR3.y*h3.y + WR3.z*h3.z + WR3.w*h3.w;
        ar += WR4.x*h4v.x + WR4.y*h4v.y + WR4.z*h4v.z + WR4.w*h4v.w;
        ar += WR5.x*h5.x + WR5.y*h5.y + WR5.z*h5.z + WR5.w*h5.w;
        ar += WR6.x*h6.x + WR6.y*h6.y + WR6.z*h6.z + WR6.w*h6.w;
        ar += WR7.x*h7.x + WR7.y*h7.y + WR7.z*h7.z + WR7.w*h7.w;
        az  = WZ0.x*h0.x + WZ0.y*h0.y + WZ0.z*h0.z + WZ0.w*h0.w;
        az += WZ1.x*h1.x + WZ1.y*h1.y + WZ1.z*h1.z + WZ1.w*h1.w;
        az += WZ2.x*h2.x + WZ2.y*h2.y + WZ2.z*h2.z + WZ2.w*h2.w;
        az += WZ3.x*h3.x + WZ3.y*h3.y + WZ3.z*h3.z + WZ3.w*h3.w;
        az += WZ4.x*h4v.x + WZ4.y*h4v.y + WZ4.z*h4v.z + WZ4.w*h4v.w;
        az += WZ5.x*h5.x + WZ5.y*h5.y + WZ5.z*h5.z + WZ5.w*h5.w;
        az += WZ6.x*h6.x + WZ6.y*h6.y + WZ6.z*h6.z + WZ6.w*h6.w;
        az += WZ7.x*h7.x + WZ7.y*h7.y + WZ7.z*h7.z + WZ7.w*h7.w;
        an  = WN0.x*h0.x + WN0.y*h0.y + WN0.z*h0.z + WN0.w*h0.w;
        an += WN1.x*h1.x + WN1.y*h1.y + WN1.z*h1.z + WN1.w*h1.w;
        an += WN2.x*h2.x + WN2.y*h2.y + WN2.z*h2.z + WN2.w*h2.w;
        an += WN3.x*h3.x + WN3.y*h3.y + WN3.z*h3.z + WN3.w*h3.w;
        an += WN4.x*h4v.x + WN4.y*h4v.y + WN4.z*h4v.z + WN4.w*h4v.w;
        an += WN5.x*h5.x + WN5.y*h5.y + WN5.z*h5.z + WN5.w*h5.w;
        an += WN6.x*h6.x + WN6.y*h6.y + WN6.z*h6.z + WN6.w*h6.w;
        an += WN7.x*h7.x + WN7.y*h7.y + WN7.z*h7.z + WN7.w*h7.w;

        // butterfly reduce within the 16-lane quarter-wave
        #pragma unroll
        for (int m = 1; m < 16; m <<= 1) {
            ar += __shfl_xor(ar, m, 64);
            az += __shfl_xor(az, m, 64);
            an += __shfl_xor(an, m, 64);
        }

        float rg = __fdividef(1.f, 1.f + __expf(-(gxr + ar)));
        float zg = __fdividef(1.f, 1.f + __expf(-(gxz + az)));
        float nx = gxn + rg * (an + bhn);
        float ng = 1.f - __fdividef(2.f, 1.f + __expf(2.f * nx));  // tanh
        float hold = h_lds[p][row & (HID - 1)];   // broadcast read of own row
        float hn = (1.f - zg) * ng + zg * hold;

        if (ll == 0) {
            unsigned long long wo =
                ((unsigned long long)(unsigned)(t + 1) << 32) |
                (unsigned long long)__float_as_uint(hn);
            __hip_atomic_store(&hbuf[(1 - p) * HID + row], wo,
                               __ATOMIC_RELAXED, __HIP_MEMORY_SCOPE_AGENT);
        }
        // no trailing barrier: next step stages into h_lds[1-p]
    }

    // ---- epilogue: WG 0 computes out = W_out @ h_T + b_out ----
    if (r == 0) {
        // h_{S_LEN} lives in parity 0 with tag S_LEN
        if (tid < HID) {
            unsigned long long hw;
            do {
                hw = __hip_atomic_load(&hbuf[0 * HID + tid], __ATOMIC_RELAXED,
                                       __HIP_MEMORY_SCOPE_AGENT);
            } while ((unsigned)(hw >> 32) != (unsigned)S_LEN);
            h_lds[0][tid] = __uint_as_float((unsigned)hw);
        }
        __syncthreads();
        // wave w computes out[w] (NOUT == 8 == waves per WG)
        float s = 0.f;
        #pragma unroll
        for (int m = 0; m < 8; ++m) {
            int j = l + 64 * m;
            s += W_out[w * HID + j] * h_lds[0][j];
        }
        #pragma unroll
        for (int m = 1; m < 64; m <<= 1) s += __shfl_xor(s, m, 64);
        if (l == 0) out[w] = s + b_out[w];
    }
}

extern "C" void kernel_launch(void* const* d_in, const int* in_sizes, int n_in,
                              void* d_out, int out_size, void* d_ws, size_t ws_size,
                              hipStream_t stream) {
    const int*   seq   = (const int*)d_in[0];
    const float* emb   = (const float*)d_in[1];
    const float* W_ih  = (const float*)d_in[2];
    const float* W_hh  = (const float*)d_in[3];
    const float* b_ih  = (const float*)d_in[4];
    const float* b_hh  = (const float*)d_in[5];
    const float* W_out = (const float*)d_in[6];
    const float* b_out = (const float*)d_in[7];
    float* ws = (float*)d_ws;
    float* out = (float*)d_out;

    gru_precompute_kernel<<<36, 256, 0, stream>>>(emb, W_ih, b_ih, ws);
    gru_persistent_kernel<<<NWG, NTHR, 0, stream>>>(seq, W_hh, b_hh, W_out, b_out,
                                                    ws, out);
}